// Round 3
// baseline (81.187 us; speedup 1.0000x reference)
//
#include <hip/hip_runtime.h>
#include <hip/hip_bf16.h>
#include <stdint.h>

// out[b,j] = sum_{i,k} softmax(alphas[i,j,:])[k] * coeffs[i,j,k] * prim_k(x[b,i])
//         == P @ W2,  P[b, kg] = prim_op(x[b,i]),  W2[kg][j]
// k-ordering remapped so the MFMA A-fragment is one cacheline/lane:
//   kg = c*32 + quad*8 + j   <->   i = quad*16 + c , op = j     (c=0..15, quad=0..3)
// A-fragment (16x16x32: lane = m + 16*quad holds A[m][quad*8+j]):
//   lane (m,quad) supplies prim_j(x[row m][col quad*16 + c]) at step c
//   -> lane loads x[row][16q..16q+15] (64B) into registers; prims in regs, no LDS.
// B-side: each block computes W2 = softmax(alphas)*coeffs DIRECTLY into its own
//   LDS in B-fragment order (redundant per block, but alphas/coeffs = 262KB
//   L2-hot; overlaps the x HBM load latency). SINGLE kernel, d_ws unused.
// Step-c/tile-t B read: wlds + c*2048 + t*512 + lane*8 -> contiguous 1KB/wave
//   ds_read_b128, conflict-free.
// C/D layout: col=lane&15, row=quad*4+reg (m89-verified).

typedef __bf16 bf16x8 __attribute__((ext_vector_type(8)));
typedef float f32x4 __attribute__((ext_vector_type(4)));

__global__ __launch_bounds__(512, 4) void darts_fused(const float* __restrict__ x,
                                                      const float* __restrict__ alphas,
                                                      const float* __restrict__ coeffs,
                                                      float* __restrict__ out) {
    __shared__ __bf16 wlds[32768];   // 64 KB, B-fragment order -> 2 blocks/CU

    const int tid  = threadIdx.x;
    const int lane = tid & 63;
    const int wv   = tid >> 6;       // 0..7
    const int m    = lane & 15;      // A-row within 16-tile
    const int q    = lane >> 4;      // quad

    // ---- phase A: issue x loads first (HBM latency hides behind phase B) ----
    const int row = blockIdx.x * 128 + wv * 16 + m;
    const float* xp = x + row * 64 + q * 16;
    f32x4 xr0 = *(const f32x4*)(xp + 0);
    f32x4 xr1 = *(const f32x4*)(xp + 4);
    f32x4 xr2 = *(const f32x4*)(xp + 8);
    f32x4 xr3 = *(const f32x4*)(xp + 12);

    // ---- phase B: build W2 into LDS (softmax gate * coeff, bf16) ------------
    // 4096 (i,n) pairs / 512 threads = 8 each; g = u*512+tid keeps the 32B
    // alphas/coeffs reads contiguous across consecutive threads.
#pragma unroll
    for (int u = 0; u < 8; ++u) {
        const int g = u * 512 + tid;        // g = i*64 + n
        const int i = g >> 6;
        const int n = g & 63;
        const float* a  = alphas + g * 8;
        const float* cf = coeffs + g * 8;

        float av[8], mx = -1e30f;
#pragma unroll
        for (int k = 0; k < 8; ++k) { av[k] = a[k]; mx = fmaxf(mx, av[k]); }
        float e[8], s = 0.f;
#pragma unroll
        for (int k = 0; k < 8; ++k) { e[k] = __expf(av[k] - mx); s += e[k]; }
        const float inv = 1.0f / s;

        bf16x8 w;
#pragma unroll
        for (int k = 0; k < 8; ++k) w[k] = (__bf16)(e[k] * inv * cf[k]);

        // i = quad*16 + step ; n = tile*16 + nl  -> fragment-order position
        const int qq = i >> 4, cc = i & 15, t = n >> 4, nl = n & 63 & 15;
        *(bf16x8*)(wlds + ((cc * 4 + t) * 64 + qq * 16 + nl) * 8) = w;
    }
    __syncthreads();

    // ---- phase C: MFMA main loop -------------------------------------------
    float xa[16];
#pragma unroll
    for (int c = 0; c < 4; ++c) { xa[c] = xr0[c]; xa[4+c] = xr1[c]; xa[8+c] = xr2[c]; xa[12+c] = xr3[c]; }

    f32x4 acc0 = {0.f, 0.f, 0.f, 0.f};
    f32x4 acc1 = {0.f, 0.f, 0.f, 0.f};
    f32x4 acc2 = {0.f, 0.f, 0.f, 0.f};
    f32x4 acc3 = {0.f, 0.f, 0.f, 0.f};

#pragma unroll
    for (int c = 0; c < 16; ++c) {
        const float xv = xa[c];
        const float x2 = xv * xv;
        bf16x8 a;
        a[0] = (__bf16)0.0f;                      // 'none'
        a[1] = (__bf16)xv;                        // linear
        a[2] = (__bf16)x2;                        // x^2
        a[3] = (__bf16)(x2 * xv);                 // x^3
        a[4] = (__bf16)__expf(xv);                // exp
        a[5] = (__bf16)__logf(xv);                // ln
        a[6] = (__bf16)__builtin_amdgcn_rcpf(xv); // 1/x
        a[7] = (__bf16)__sinf(xv);                // sin

        const __bf16* bb = wlds + c * 2048 + lane * 8;
        bf16x8 b0 = *(const bf16x8*)(bb);
        bf16x8 b1 = *(const bf16x8*)(bb + 512);
        bf16x8 b2 = *(const bf16x8*)(bb + 1024);
        bf16x8 b3 = *(const bf16x8*)(bb + 1536);
        acc0 = __builtin_amdgcn_mfma_f32_16x16x32_bf16(a, b0, acc0, 0, 0, 0);
        acc1 = __builtin_amdgcn_mfma_f32_16x16x32_bf16(a, b1, acc1, 0, 0, 0);
        acc2 = __builtin_amdgcn_mfma_f32_16x16x32_bf16(a, b2, acc2, 0, 0, 0);
        acc3 = __builtin_amdgcn_mfma_f32_16x16x32_bf16(a, b3, acc3, 0, 0, 0);
    }

    // ---- epilogue: C layout col=lane&15, row=q*4+r -------------------------
    float* orow = out + (blockIdx.x * 128 + wv * 16 + q * 4) * 64 + m;
#pragma unroll
    for (int r = 0; r < 4; ++r) {
        orow[r * 64 + 0]  = acc0[r];
        orow[r * 64 + 16] = acc1[r];
        orow[r * 64 + 32] = acc2[r];
        orow[r * 64 + 48] = acc3[r];
    }
}

extern "C" void kernel_launch(void* const* d_in, const int* in_sizes, int n_in,
                              void* d_out, int out_size, void* d_ws, size_t ws_size,
                              hipStream_t stream) {
    const float* x      = (const float*)d_in[0];
    const float* alphas = (const float*)d_in[1];
    const float* coeffs = (const float*)d_in[2];
    float* out = (float*)d_out;
    (void)d_ws; (void)ws_size;

    darts_fused<<<512, 512, 0, stream>>>(x, alphas, coeffs, out);
}